// Round 3
// baseline (178.308 us; speedup 1.0000x reference)
//
#include <hip/hip_runtime.h>
#include <math.h>

#define RANK 33
#define D 32            // rank-1 (space dims)
#define N_ENT 50000
#define N_PAD 50048     // 782 * 64
#define N_REL 500
#define NQ 2000
#define M_PAD 2048      // 32 * 64
#define KP 64           // K padded 33 -> 64

typedef float  f32x4  __attribute__((ext_vector_type(4)));
typedef short  bf16x8 __attribute__((ext_vector_type(8)));

__device__ __forceinline__ float waveReduceSum(float v) {
    #pragma unroll
    for (int off = 32; off > 0; off >>= 1)
        v += __shfl_xor(v, off, 64);
    return v;
}

__device__ __forceinline__ ushort f2bf(float f) {  // RTN-even
    union { float f; unsigned u; } c; c.f = f;
    return (ushort)((c.u + 0x7fffu + ((c.u >> 16) & 1u)) >> 16);
}

// ---------------- K1: expmap0 -> emb_bf16[N_PAD][KP], row-major, coalesced writes.
// One wave per entity; lane-pair shuffle pack -> 128 B contiguous per row.
__global__ void k_expmap(const float* __restrict__ ent, ushort* __restrict__ embB) {
    int wave = (blockIdx.x * blockDim.x + threadIdx.x) >> 6;
    int lane = threadIdx.x & 63;
    if (wave >= N_PAD) return;
    float val = 0.0f;
    if (wave < N_ENT) {
        const float* u = ent + (long)wave * RANK;
        float uv = (lane < RANK) ? u[lane] : 0.0f;
        float en = sqrtf(waveReduceSum(uv * uv));
        float scale = fminf(1.0f, 2.0f / fmaxf(en, 1e-12f));
        uv *= scale;
        float sp2 = waveReduceSum((lane >= 1 && lane < RANK) ? uv * uv : 0.0f);
        float u0 = __shfl(uv, 0, 64);
        float nomin = sqrtf(fmaxf(sp2 - u0 * u0, 1e-8f));
        float s = sinhf(nomin) / nomin;
        float sv = s * uv;
        float t2 = waveReduceSum((lane >= 1 && lane < RANK) ? sv * sv : 0.0f);
        val = (lane == 0) ? sqrtf(1.0f + t2) : ((lane < RANK) ? sv : 0.0f);
    }
    float v0 = __shfl(val, (lane & 31) * 2, 64);
    float v1 = __shfl(val, (lane & 31) * 2 + 1, 64);
    if (lane < 32) {
        ushort2 p; p.x = f2bf(v0); p.y = f2bf(v1);
        *(ushort2*)(embB + (size_t)wave * KP + lane * 2) = p;
    }
}

// ---------------- K2: per-query transform -> lhs_bf16[M_PAD][KP] (rows pre-scaled by -2).
// One wave per query; expmap0 of the head entity recomputed inline.
__global__ void k_query(const float* __restrict__ ent,
                        const float* __restrict__ rot_raw,
                        const float* __restrict__ boosts,
                        const int* __restrict__ queries,
                        ushort* __restrict__ lhsB) {
    int wave = (blockIdx.x * blockDim.x + threadIdx.x) >> 6;
    int lane = threadIdx.x & 63;
    if (wave >= M_PAD) return;
    float outv = 0.0f;
    if (wave < NQ) {
        int h = queries[wave * 3 + 0];
        int r = queries[wave * 3 + 1];
        // expmap0(ent[h])
        const float* u = ent + (long)h * RANK;
        float uv = (lane < RANK) ? u[lane] : 0.0f;
        float en = sqrtf(waveReduceSum(uv * uv));
        float scale = fminf(1.0f, 2.0f / fmaxf(en, 1e-12f));
        uv *= scale;
        float sp2 = waveReduceSum((lane >= 1 && lane < RANK) ? uv * uv : 0.0f);
        float u0 = __shfl(uv, 0, 64);
        float nomin = sqrtf(fmaxf(sp2 - u0 * u0, 1e-8f));
        float s = sinhf(nomin) / nomin;
        float sv = s * uv;
        float t2 = waveReduceSum((lane >= 1 && lane < RANK) ? sv * sv : 0.0f);
        float lhs_t = sqrtf(1.0f + t2);
        // lane i < 32 owns space dim i
        float x = __shfl(sv, (lane + 1) & 63, 64);
        if (lane >= D) x = 0.0f;
        // x^T (H_0..H_31) = H_31(..(H_0 x))  (each H_k symmetric)
        const float* rr = rot_raw + (long)r * D * D;
        for (int k = 0; k < D; ++k) {
            float g = 0.0f;
            if (lane < D) {
                float w = rr[k * D + lane];
                g = 0.5f * w * (1.0f + erff(w * 0.70710678118654752f)); // exact gelu
            }
            float dvx = waveReduceSum(g * x);
            float n   = waveReduceSum(g * g);
            x -= (2.0f * dvx / n) * g;
        }
        // Lorentz boost
        float b = 0.0f;
        if (lane < D) b = tanhf(boosts[(long)r * D + lane]) * (1.0f / 33.0f);
        float b2   = waveReduceSum(b * b);
        float bdot = waveReduceSum(b * x);
        float zeta = 1.0f / (sqrtf(1.0f - b2) + 1e-8f);
        float x0 = zeta * lhs_t - zeta * bdot;
        float xr = -zeta * lhs_t * b + x + (zeta - 1.0f) / (b2 + 1e-9f) * b * bdot;
        // row = -2 * lhs_neg = [2*x0, -2*xr...]
        float xr_sh = __shfl(xr, (lane + 63) & 63, 64);
        outv = (lane == 0) ? 2.0f * x0 : ((lane < RANK) ? -2.0f * xr_sh : 0.0f);
    }
    float v0 = __shfl(outv, (lane & 31) * 2, 64);
    float v1 = __shfl(outv, (lane & 31) * 2 + 1, 64);
    if (lane < 32) {
        ushort2 p; p.x = f2bf(v0); p.y = f2bf(v1);
        *(ushort2*)(lhsB + (size_t)wave * KP + lane * 2) = p;
    }
}

// ---------------- K3: scores = acc_init(2.0) + (-2*lhs_neg) @ emb^T  via bf16 MFMA.
// Block = 4 waves; wave w owns rows m0+w*16..+15, 64 n-cols (4 MFMA n-tiles).
// A-frag: lane reads lhs[m0+(l&15)][(l>>4)*8 ..+7]; B-frag: emb[n+(l&15)][(l>>4)*8 ..+7].
__global__ void k_scores(const ushort* __restrict__ lhsB,
                         const ushort* __restrict__ embB,
                         float* __restrict__ out) {
    int wid  = threadIdx.x >> 6;
    int lane = threadIdx.x & 63;
    int m0 = blockIdx.x * 64 + wid * 16;
    int n0 = blockIdx.y * 64;
    int lr = lane & 15, lk = (lane >> 4) * 8;

    const ushort* arow = lhsB + (size_t)(m0 + lr) * KP + lk;
    bf16x8 a0 = *(const bf16x8*)(arow);
    bf16x8 a1 = *(const bf16x8*)(arow + 32);

    f32x4 acc[4];
    #pragma unroll
    for (int nt = 0; nt < 4; ++nt) acc[nt] = f32x4{2.f, 2.f, 2.f, 2.f};

    #pragma unroll
    for (int nt = 0; nt < 4; ++nt) {
        const ushort* brow = embB + (size_t)(n0 + nt * 16 + lr) * KP + lk;
        bf16x8 b0 = *(const bf16x8*)(brow);
        bf16x8 b1 = *(const bf16x8*)(brow + 32);
        acc[nt] = __builtin_amdgcn_mfma_f32_16x16x32_bf16(a0, b0, acc[nt], 0, 0, 0);
        acc[nt] = __builtin_amdgcn_mfma_f32_16x16x32_bf16(a1, b1, acc[nt], 0, 0, 0);
    }

    // C/D: col = lane&15, row = (lane>>4)*4 + reg
    int r0 = m0 + (lane >> 4) * 4;
    #pragma unroll
    for (int nt = 0; nt < 4; ++nt) {
        int c = n0 + nt * 16 + lr;
        if (c < N_ENT) {
            #pragma unroll
            for (int r = 0; r < 4; ++r) {
                int row = r0 + r;
                if (row < NQ)
                    __builtin_nontemporal_store(acc[nt][r], out + (size_t)row * N_ENT + c);
            }
        }
    }
}

// ---------------- K4a: per-relation norms (raw rot Frobenius + boost L2).
__global__ void k_norms(const float* __restrict__ rot_raw,
                        const float* __restrict__ boosts,
                        float* __restrict__ rotF, float* __restrict__ boostN) {
    int wave = (blockIdx.x * blockDim.x + threadIdx.x) >> 6;
    int lane = threadIdx.x & 63;
    if (wave >= N_REL) return;
    const float* rr = rot_raw + (long)wave * (D * D);
    float s = 0.0f;
    #pragma unroll
    for (int i = 0; i < (D * D) / 64; ++i) {
        float w = rr[i * 64 + lane];
        s += w * w;
    }
    s = waveReduceSum(s);
    float sb = 0.0f;
    if (lane < D) { float w = boosts[(long)wave * D + lane]; sb = w * w; }
    sb = waveReduceSum(sb);
    if (lane == 0) { rotF[wave] = sqrtf(s); boostN[wave] = sqrtf(sb); }
}

// ---------------- K4b: reg[i,j] = rotF[j] + boostN[i]
__global__ void k_reg(const float* __restrict__ rotF, const float* __restrict__ boostN,
                      float* __restrict__ out) {
    int idx = blockIdx.x * blockDim.x + threadIdx.x;
    if (idx >= N_REL * N_REL) return;
    int i = idx / N_REL;
    int j = idx - i * N_REL;
    out[idx] = rotF[j] + boostN[i];
}

extern "C" void kernel_launch(void* const* d_in, const int* in_sizes, int n_in,
                              void* d_out, int out_size, void* d_ws, size_t ws_size,
                              hipStream_t stream) {
    const float* ent     = (const float*)d_in[0];   // 50000 x 33
    const float* rot     = (const float*)d_in[1];   // 500 x 32 x 32
    const float* boosts  = (const float*)d_in[2];   // 500 x 32
    const int*   queries = (const int*)d_in[3];     // 2000 x 3 (h, r, t)
    float* out = (float*)d_out;                     // scores (2000x50000) ++ reg (500x500)

    ushort* embB = (ushort*)d_ws;                        // N_PAD * 64 bf16 = 6.4 MB
    ushort* lhsB = embB + (size_t)N_PAD * KP;            // M_PAD * 64 bf16 = 256 KB
    float*  rotF   = (float*)(lhsB + (size_t)M_PAD * KP);
    float*  boostN = rotF + N_REL;

    hipLaunchKernelGGL(k_expmap, dim3(N_PAD / 4), dim3(256), 0, stream, ent, embB);
    hipLaunchKernelGGL(k_query, dim3(M_PAD / 4), dim3(256), 0, stream,
                       ent, rot, boosts, queries, lhsB);
    hipLaunchKernelGGL(k_scores, dim3(M_PAD / 64, N_PAD / 64), dim3(256), 0, stream,
                       lhsB, embB, out);
    hipLaunchKernelGGL(k_norms, dim3((N_REL + 3) / 4), dim3(256), 0, stream,
                       rot, boosts, rotF, boostN);
    hipLaunchKernelGGL(k_reg, dim3((N_REL * N_REL + 255) / 256), dim3(256), 0, stream,
                       rotF, boostN, out + (size_t)NQ * N_ENT);
}

// Round 4
// 175.356 us; speedup vs baseline: 1.0168x; 1.0168x over previous
//
#include <hip/hip_runtime.h>
#include <math.h>

#define RANK 33
#define D 32            // rank-1 (space dims)
#define N_ENT 50000
#define N_PAD 50048     // 782 * 64
#define N_REL 500
#define NQ 2000
#define M_PAD 2048      // 32 * 64
#define KP 64           // K padded 33 -> 64

typedef float  f32x4  __attribute__((ext_vector_type(4)));
typedef short  bf16x8 __attribute__((ext_vector_type(8)));

__device__ __forceinline__ float waveReduceSum(float v) {
    #pragma unroll
    for (int off = 32; off > 0; off >>= 1)
        v += __shfl_xor(v, off, 64);
    return v;
}

__device__ __forceinline__ ushort f2bf(float f) {  // RTN-even
    union { float f; unsigned u; } c; c.f = f;
    return (ushort)((c.u + 0x7fffu + ((c.u >> 16) & 1u)) >> 16);
}

// ---------------- K1: expmap0 -> emb_bf16[N_PAD][KP], row-major, coalesced writes.
__global__ void k_expmap(const float* __restrict__ ent, ushort* __restrict__ embB) {
    int wave = (blockIdx.x * blockDim.x + threadIdx.x) >> 6;
    int lane = threadIdx.x & 63;
    if (wave >= N_PAD) return;
    float val = 0.0f;
    if (wave < N_ENT) {
        const float* u = ent + (long)wave * RANK;
        float uv = (lane < RANK) ? u[lane] : 0.0f;
        float en = sqrtf(waveReduceSum(uv * uv));
        float scale = fminf(1.0f, 2.0f / fmaxf(en, 1e-12f));
        uv *= scale;
        float sp2 = waveReduceSum((lane >= 1 && lane < RANK) ? uv * uv : 0.0f);
        float u0 = __shfl(uv, 0, 64);
        float nomin = sqrtf(fmaxf(sp2 - u0 * u0, 1e-8f));
        float s = sinhf(nomin) / nomin;
        float sv = s * uv;
        float t2 = waveReduceSum((lane >= 1 && lane < RANK) ? sv * sv : 0.0f);
        val = (lane == 0) ? sqrtf(1.0f + t2) : ((lane < RANK) ? sv : 0.0f);
    }
    float v0 = __shfl(val, (lane & 31) * 2, 64);
    float v1 = __shfl(val, (lane & 31) * 2 + 1, 64);
    if (lane < 32) {
        ushort2 p; p.x = f2bf(v0); p.y = f2bf(v1);
        *(ushort2*)(embB + (size_t)wave * KP + lane * 2) = p;
    }
}

// ---------------- K2: per-query transform -> lhs_bf16[M_PAD][KP] (rows pre-scaled by -2).
__global__ void k_query(const float* __restrict__ ent,
                        const float* __restrict__ rot_raw,
                        const float* __restrict__ boosts,
                        const int* __restrict__ queries,
                        ushort* __restrict__ lhsB) {
    int wave = (blockIdx.x * blockDim.x + threadIdx.x) >> 6;
    int lane = threadIdx.x & 63;
    if (wave >= M_PAD) return;
    float outv = 0.0f;
    if (wave < NQ) {
        int h = queries[wave * 3 + 0];
        int r = queries[wave * 3 + 1];
        // expmap0(ent[h])
        const float* u = ent + (long)h * RANK;
        float uv = (lane < RANK) ? u[lane] : 0.0f;
        float en = sqrtf(waveReduceSum(uv * uv));
        float scale = fminf(1.0f, 2.0f / fmaxf(en, 1e-12f));
        uv *= scale;
        float sp2 = waveReduceSum((lane >= 1 && lane < RANK) ? uv * uv : 0.0f);
        float u0 = __shfl(uv, 0, 64);
        float nomin = sqrtf(fmaxf(sp2 - u0 * u0, 1e-8f));
        float s = sinhf(nomin) / nomin;
        float sv = s * uv;
        float t2 = waveReduceSum((lane >= 1 && lane < RANK) ? sv * sv : 0.0f);
        float lhs_t = sqrtf(1.0f + t2);
        // lane i < 32 owns space dim i
        float x = __shfl(sv, (lane + 1) & 63, 64);
        if (lane >= D) x = 0.0f;
        // x^T (H_0..H_31) = H_31(..(H_0 x))  (each H_k symmetric)
        const float* rr = rot_raw + (long)r * D * D;
        for (int k = 0; k < D; ++k) {
            float g = 0.0f;
            if (lane < D) {
                float w = rr[k * D + lane];
                g = 0.5f * w * (1.0f + erff(w * 0.70710678118654752f)); // exact gelu
            }
            float dvx = waveReduceSum(g * x);
            float n   = waveReduceSum(g * g);
            x -= (2.0f * dvx / n) * g;
        }
        // Lorentz boost
        float b = 0.0f;
        if (lane < D) b = tanhf(boosts[(long)r * D + lane]) * (1.0f / 33.0f);
        float b2   = waveReduceSum(b * b);
        float bdot = waveReduceSum(b * x);
        float zeta = 1.0f / (sqrtf(1.0f - b2) + 1e-8f);
        float x0 = zeta * lhs_t - zeta * bdot;
        float xr = -zeta * lhs_t * b + x + (zeta - 1.0f) / (b2 + 1e-9f) * b * bdot;
        // row = -2 * lhs_neg = [2*x0, -2*xr...]
        float xr_sh = __shfl(xr, (lane + 63) & 63, 64);
        outv = (lane == 0) ? 2.0f * x0 : ((lane < RANK) ? -2.0f * xr_sh : 0.0f);
    }
    float v0 = __shfl(outv, (lane & 31) * 2, 64);
    float v1 = __shfl(outv, (lane & 31) * 2 + 1, 64);
    if (lane < 32) {
        ushort2 p; p.x = f2bf(v0); p.y = f2bf(v1);
        *(ushort2*)(lhsB + (size_t)wave * KP + lane * 2) = p;
    }
}

// ---------------- K3: scores via bf16 MFMA, LDS-staged epilogue for full-line stores.
// Block = 4 waves, tile 64m x 64n. Wave w: rows m0+w*16..+15 across 4 n-tiles.
__global__ void k_scores(const ushort* __restrict__ lhsB,
                         const ushort* __restrict__ embB,
                         float* __restrict__ out) {
    __shared__ float lds[64 * 65];
    int wid  = threadIdx.x >> 6;
    int lane = threadIdx.x & 63;
    int mb = blockIdx.x * 64;
    int m0 = mb + wid * 16;
    int n0 = blockIdx.y * 64;
    int lr = lane & 15, rg = lane >> 4;

    const ushort* arow = lhsB + (size_t)(m0 + lr) * KP + rg * 8;
    bf16x8 a0 = *(const bf16x8*)(arow);
    bf16x8 a1 = *(const bf16x8*)(arow + 32);

    f32x4 acc[4];
    #pragma unroll
    for (int nt = 0; nt < 4; ++nt) acc[nt] = f32x4{2.f, 2.f, 2.f, 2.f};

    #pragma unroll
    for (int nt = 0; nt < 4; ++nt) {
        const ushort* brow = embB + (size_t)(n0 + nt * 16 + lr) * KP + rg * 8;
        bf16x8 b0 = *(const bf16x8*)(brow);
        bf16x8 b1 = *(const bf16x8*)(brow + 32);
        acc[nt] = __builtin_amdgcn_mfma_f32_16x16x32_bf16(a0, b0, acc[nt], 0, 0, 0);
        acc[nt] = __builtin_amdgcn_mfma_f32_16x16x32_bf16(a1, b1, acc[nt], 0, 0, 0);
    }

    // C/D: col = lane&15, row = (lane>>4)*4 + reg  -> stage in LDS (stride 65)
    #pragma unroll
    for (int nt = 0; nt < 4; ++nt)
        #pragma unroll
        for (int r = 0; r < 4; ++r)
            lds[(wid * 16 + rg * 4 + r) * 65 + nt * 16 + lr] = acc[nt][r];
    __syncthreads();

    // Coalesced store: thread -> one float4; wave-instr = 4 rows x 256 B contiguous.
    int trow = threadIdx.x >> 4;
    int tcol = (threadIdx.x & 15) * 4;
    bool fullN = (n0 + 64 <= N_ENT);
    #pragma unroll
    for (int p = 0; p < 4; ++p) {
        int row  = p * 16 + trow;
        int grow = mb + row;
        if (grow < NQ) {
            f32x4 v = *(const f32x4*)&lds[row * 65 + tcol];
            if (fullN) {
                __builtin_nontemporal_store(v, (f32x4*)(out + (size_t)grow * N_ENT + n0 + tcol));
            } else {
                #pragma unroll
                for (int j = 0; j < 4; ++j)
                    if (n0 + tcol + j < N_ENT)
                        out[(size_t)grow * N_ENT + n0 + tcol + j] = v[j];
            }
        }
    }
}

// ---------------- K4a: per-relation norms (raw rot Frobenius + boost L2).
__global__ void k_norms(const float* __restrict__ rot_raw,
                        const float* __restrict__ boosts,
                        float* __restrict__ rotF, float* __restrict__ boostN) {
    int wave = (blockIdx.x * blockDim.x + threadIdx.x) >> 6;
    int lane = threadIdx.x & 63;
    if (wave >= N_REL) return;
    const float* rr = rot_raw + (long)wave * (D * D);
    float s = 0.0f;
    #pragma unroll
    for (int i = 0; i < (D * D) / 64; ++i) {
        float w = rr[i * 64 + lane];
        s += w * w;
    }
    s = waveReduceSum(s);
    float sb = 0.0f;
    if (lane < D) { float w = boosts[(long)wave * D + lane]; sb = w * w; }
    sb = waveReduceSum(sb);
    if (lane == 0) { rotF[wave] = sqrtf(s); boostN[wave] = sqrtf(sb); }
}

// ---------------- K4b: reg[i,j] = rotF[j] + boostN[i]
__global__ void k_reg(const float* __restrict__ rotF, const float* __restrict__ boostN,
                      float* __restrict__ out) {
    int idx = blockIdx.x * blockDim.x + threadIdx.x;
    if (idx >= N_REL * N_REL) return;
    int i = idx / N_REL;
    int j = idx - i * N_REL;
    out[idx] = rotF[j] + boostN[i];
}

extern "C" void kernel_launch(void* const* d_in, const int* in_sizes, int n_in,
                              void* d_out, int out_size, void* d_ws, size_t ws_size,
                              hipStream_t stream) {
    const float* ent     = (const float*)d_in[0];   // 50000 x 33
    const float* rot     = (const float*)d_in[1];   // 500 x 32 x 32
    const float* boosts  = (const float*)d_in[2];   // 500 x 32
    const int*   queries = (const int*)d_in[3];     // 2000 x 3 (h, r, t)
    float* out = (float*)d_out;                     // scores (2000x50000) ++ reg (500x500)

    ushort* embB = (ushort*)d_ws;                        // N_PAD * 64 bf16 = 6.4 MB
    ushort* lhsB = embB + (size_t)N_PAD * KP;            // M_PAD * 64 bf16 = 256 KB
    float*  rotF   = (float*)(lhsB + (size_t)M_PAD * KP);
    float*  boostN = rotF + N_REL;

    hipLaunchKernelGGL(k_expmap, dim3(N_PAD / 4), dim3(256), 0, stream, ent, embB);
    hipLaunchKernelGGL(k_query, dim3(M_PAD / 4), dim3(256), 0, stream,
                       ent, rot, boosts, queries, lhsB);
    hipLaunchKernelGGL(k_scores, dim3(M_PAD / 64, N_PAD / 64), dim3(256), 0, stream,
                       lhsB, embB, out);
    hipLaunchKernelGGL(k_norms, dim3((N_REL + 3) / 4), dim3(256), 0, stream,
                       rot, boosts, rotF, boostN);
    hipLaunchKernelGGL(k_reg, dim3((N_REL * N_REL + 255) / 256), dim3(256), 0, stream,
                       rotF, boostN, out + (size_t)NQ * N_ENT);
}